// Round 4
// baseline (241.009 us; speedup 1.0000x reference)
//
#include <hip/hip_runtime.h>
#include <hip/hip_fp16.h>
#include <cstdint>

#define SEQ 4096
#define DIM 1024

typedef _Float16 f16x8 __attribute__((ext_vector_type(8)));
typedef float f32x16 __attribute__((ext_vector_type(16)));
typedef ushort u16x8 __attribute__((ext_vector_type(8)));
typedef __attribute__((address_space(1))) void as1_void;
typedef __attribute__((address_space(3))) void as3_void;

__device__ __forceinline__ ushort f2h(float f) {
  _Float16 h = (_Float16)f;
  return __builtin_bit_cast(ushort, h);
}
__device__ __forceinline__ float h2f(ushort u) {
  return (float)__builtin_bit_cast(_Float16, u);
}

// ---------------- fused conversions: z<3 -> W transpose+cvt, z==3 -> X cvt ----------------
__global__ void convert_all_kernel(const float* __restrict__ X, const float* __restrict__ Wk,
                                   const float* __restrict__ Wv, const float* __restrict__ Wq,
                                   ushort* __restrict__ Xh, ushort* __restrict__ Wt) {
  const int z = blockIdx.z;
  const int tx = threadIdx.x, ty = threadIdx.y;  // (32,8)
  if (z == 3) {
    const int bid = blockIdx.y * 32 + blockIdx.x;
    const int t = ty * 32 + tx;
#pragma unroll
    for (int k = 0; k < 4; k++) {
      int i = bid * 1024 + k * 256 + t;
      float4 v = reinterpret_cast<const float4*>(X)[i];
      ushort4 o = { f2h(v.x), f2h(v.y), f2h(v.z), f2h(v.w) };
      reinterpret_cast<ushort4*>(Xh)[i] = o;
    }
    return;
  }
  __shared__ float tile[32][33];
  const float* W = (z == 0) ? Wk : (z == 1) ? Wv : Wq;
  int n0 = blockIdx.x * 32, k0 = blockIdx.y * 32;
#pragma unroll
  for (int r = 0; r < 4; r++) {
    int k = ty + r * 8;
    tile[k][tx] = W[(size_t)(k0 + k) * DIM + n0 + tx];
  }
  __syncthreads();
  ushort* out = Wt + (size_t)z * DIM * DIM;
#pragma unroll
  for (int r = 0; r < 4; r++) {
    int n = ty + r * 8;
    out[(size_t)(n0 + n) * DIM + k0 + tx] = f2h(tile[tx][n]);
  }
}

// ---------------- 256x256 GEMM (R1 best-measured schedule), optional row-stats epilogue ----
// C[m,n] = sum_k A[m,k]*B[n,k]  (both operands K-contiguous), fp16 out.
// 4 k-slice phases per K-tile; prefetch at ks0/ks1 into other buffer; boundary sync.
// XOR chunk swizzle key(r)=(r&7)^((r>>3)&3); 0 bank conflicts (verified).
// STATS: per-row block-local (max, sum(exp)) over this block's 256 cols, computed from
// acc rounded through f16 (exactly matching stored S), written to Stats[cb*SEQ + row].
template <bool STATS>
__device__ __forceinline__ void gemm_tile256(const ushort* __restrict__ A,
                                             const ushort* __restrict__ B,
                                             ushort* __restrict__ C,
                                             int N, int K, int m0, int n0,
                                             int kt0, int ktend,
                                             float2* __restrict__ Stats, int cb) {
  constexpr int BK = 64;
  __shared__ __align__(16) ushort As[2][256 * BK];  // 2 x 32 KB
  __shared__ __align__(16) ushort Bs[2][256 * BK];  // 2 x 32 KB
  const int tid = threadIdx.x;                       // [0,512)
  const int wave = tid >> 6, lane = tid & 63;
  const int l31 = lane & 31, khalf = lane >> 5;
  const int wm = (wave & 1) * 128, wn = (wave >> 1) * 64;

  const int srow = tid >> 3;                         // [0,64)
  const int skey = ((srow & 7) ^ ((srow >> 3) & 3));
  const int sce = (((tid & 7) ^ skey) * 8);
  const int rk = (l31 & 7) ^ ((l31 >> 3) & 3);

  f32x16 acc[4][2];
#pragma unroll
  for (int i = 0; i < 4; i++)
#pragma unroll
    for (int j = 0; j < 2; j++)
#pragma unroll
      for (int r = 0; r < 16; r++) acc[i][j][r] = 0.f;

  const ushort* Abase = A + (size_t)(m0 + srow) * K + sce;
  const ushort* Bbase = B + (size_t)(n0 + srow) * K + sce;
  const int ldsbase = wave * 512;

  const int ntiles = (ktend - kt0) >> 6;

  // prologue: stage tile 0 fully into buf 0
#pragma unroll
  for (int q = 0; q < 4; q++)
    __builtin_amdgcn_global_load_lds((const as1_void*)(Abase + (size_t)q * 64 * K + kt0),
                                     (as3_void*)&As[0][ldsbase + q * 4096], 16, 0, 0);
#pragma unroll
  for (int q = 0; q < 4; q++)
    __builtin_amdgcn_global_load_lds((const as1_void*)(Bbase + (size_t)q * 64 * K + kt0),
                                     (as3_void*)&Bs[0][ldsbase + q * 4096], 16, 0, 0);
  __syncthreads();

  for (int tt = 0; tt < ntiles; ++tt) {
    const int cur = tt & 1, nb = cur ^ 1;
    const int nkt = kt0 + (tt + 1) * BK;
    const bool pf = (tt + 1 < ntiles);
    const ushort* As_c = As[cur];
    const ushort* Bs_c = Bs[cur];
#pragma unroll
    for (int ks = 0; ks < 4; ks++) {
      f16x8 af[4], bf2[2];
      const int co = (((ks * 2 + khalf)) ^ rk) * 8;
#pragma unroll
      for (int i = 0; i < 4; i++)
        af[i] = *reinterpret_cast<const f16x8*>(&As_c[(wm + i * 32 + l31) * BK + co]);
#pragma unroll
      for (int j = 0; j < 2; j++)
        bf2[j] = *reinterpret_cast<const f16x8*>(&Bs_c[(wn + j * 32 + l31) * BK + co]);
      if (pf && ks == 0) {
#pragma unroll
        for (int q = 0; q < 4; q++)
          __builtin_amdgcn_global_load_lds((const as1_void*)(Abase + (size_t)q * 64 * K + nkt),
                                           (as3_void*)&As[nb][ldsbase + q * 4096], 16, 0, 0);
      }
      if (pf && ks == 1) {
#pragma unroll
        for (int q = 0; q < 4; q++)
          __builtin_amdgcn_global_load_lds((const as1_void*)(Bbase + (size_t)q * 64 * K + nkt),
                                           (as3_void*)&Bs[nb][ldsbase + q * 4096], 16, 0, 0);
      }
      __builtin_amdgcn_s_barrier();
      __builtin_amdgcn_s_setprio(1);
#pragma unroll
      for (int k = 0; k < 4; k++) { (void)k; }
#pragma unroll
      for (int i = 0; i < 4; i++)
#pragma unroll
        for (int j = 0; j < 2; j++)
          acc[i][j] = __builtin_amdgcn_mfma_f32_32x32x16_f16(af[i], bf2[j], acc[i][j], 0, 0, 0);
      __builtin_amdgcn_s_setprio(0);
      if (ks < 3) __builtin_amdgcn_s_barrier();
    }
    __syncthreads();  // tile boundary
  }

  // epilogue: 32x32 C/D layout col=lane&31, row=(reg&3)+8*(reg>>2)+4*(lane>>5)  [m74/m101]
#pragma unroll
  for (int i = 0; i < 4; i++)
#pragma unroll
    for (int j = 0; j < 2; j++)
#pragma unroll
      for (int r = 0; r < 16; r++) {
        int row = m0 + wm + i * 32 + (r & 3) + 8 * (r >> 2) + 4 * khalf;
        int col = n0 + wn + j * 32 + l31;
        C[(size_t)row * N + col] = f2h(acc[i][j][r]);
      }

  if constexpr (STATS) {
    // Reuse As LDS as f32 scratch: smax[256][4] @0, ssum[256][4] @1024, rowm[256] @2048.
    float* sm = reinterpret_cast<float*>(&As[0][0]);
    const int wcol = wave >> 1;
    __syncthreads();  // all MFMA reads of As done; safe to reuse
    // pass A: per-row wave-local max over 64 cols (2 j-frags x 32 lanes)
#pragma unroll
    for (int i = 0; i < 4; i++)
#pragma unroll
      for (int r = 0; r < 16; r++) {
        float a0 = h2f(f2h(acc[i][0][r]));
        float a1 = h2f(f2h(acc[i][1][r]));
        float mx = fmaxf(a0, a1);
#pragma unroll
        for (int o = 16; o > 0; o >>= 1) mx = fmaxf(mx, __shfl_xor(mx, o, 64));
        if (l31 == 0) {
          int rowl = wm + i * 32 + (r & 3) + 8 * (r >> 2) + 4 * khalf;
          sm[rowl * 4 + wcol] = mx;
        }
      }
    __syncthreads();
    if (tid < 256) {
      float rm = fmaxf(fmaxf(sm[tid * 4], sm[tid * 4 + 1]),
                       fmaxf(sm[tid * 4 + 2], sm[tid * 4 + 3]));
      sm[2048 + tid] = rm;
    }
    __syncthreads();
    // pass B: per-row wave-local sum of exp(v - rowmax)
#pragma unroll
    for (int i = 0; i < 4; i++)
#pragma unroll
      for (int r = 0; r < 16; r++) {
        int rowl = wm + i * 32 + (r & 3) + 8 * (r >> 2) + 4 * khalf;
        float rm = sm[2048 + rowl];
        float a0 = h2f(f2h(acc[i][0][r]));
        float a1 = h2f(f2h(acc[i][1][r]));
        float s = __expf(a0 - rm) + __expf(a1 - rm);
#pragma unroll
        for (int o = 16; o > 0; o >>= 1) s += __shfl_xor(s, o, 64);
        if (l31 == 0) sm[1024 + rowl * 4 + wcol] = s;
      }
    __syncthreads();
    if (tid < 256) {
      float sum = sm[1024 + tid * 4] + sm[1024 + tid * 4 + 1] +
                  sm[1024 + tid * 4 + 2] + sm[1024 + tid * 4 + 3];
      Stats[(size_t)cb * SEQ + m0 + tid] = make_float2(sm[2048 + tid], sum);
    }
  }
}

// ---------------- fused K/Q/V^T projections (256 blocks of 256^2) ----------------
__global__ __launch_bounds__(512, 2) void proj256_kernel(const ushort* __restrict__ Xh,
                                                         const ushort* __restrict__ Wt,
                                                         ushort* __restrict__ Kh,
                                                         ushort* __restrict__ Qh,
                                                         ushort* __restrict__ Vt) {
  const int b = blockIdx.x;  // [0,256)
  const ushort* A;
  const ushort* B;
  ushort* Cp;
  int N, m0, n0;
  if (b < 128) {
    const int z = b >> 6, q = b & 63;
    A = Xh;
    B = Wt + (size_t)(z ? 2 : 0) * DIM * DIM;
    Cp = z ? Qh : Kh;
    N = DIM;
    m0 = (q >> 2) * 256;
    n0 = (q & 3) * 256;
  } else {
    const int q = b - 128;                       // V^T: M=1024 x N=4096
    A = Wt + (size_t)DIM * DIM;
    B = Xh;
    Cp = Vt;
    N = SEQ;
    m0 = (q >> 4) * 256;
    n0 = (q & 15) * 256;
  }
  gemm_tile256<false>(A, B, Cp, N, DIM, m0, n0, 0, DIM, nullptr, 0);
}

// ---------------- S = K @ Q^T (fp16) + per-(row,colblock) softmax stats ----------------
__global__ __launch_bounds__(512, 2) void score256_kernel(const ushort* __restrict__ Kh,
                                                          const ushort* __restrict__ Qh,
                                                          ushort* __restrict__ S,
                                                          float2* __restrict__ Stats) {
  const int f = blockIdx.x;               // [0,256)
  const int t = (f & 7) * 32 + (f >> 3);  // XCD-contiguous (bijective)
  const int ty = t >> 4, tx = t & 15;
  gemm_tile256<true>(Kh, Qh, S, SEQ, DIM, ty * 256, tx * 256, 0, DIM, Stats, tx);
}

// ---------------- O partials: softmax applied in A-staging, split-K=4 ----------------
// A-operand = P = exp(S - m_row) * invSum_row, computed on the fly:
// reg-load S tile (issued at ks0, a full tile ahead), transform in VALU at the
// boundary, ds_write_b128 to the exact LDS offsets global_load_lds used.
__global__ __launch_bounds__(512, 2) void out_sm256_kernel(const ushort* __restrict__ S,
                                                           const ushort* __restrict__ Vt,
                                                           const float2* __restrict__ Stats,
                                                           ushort* __restrict__ Part) {
  constexpr int BK = 64;
  __shared__ __align__(16) ushort As[2][256 * BK];
  __shared__ __align__(16) ushort Bs[2][256 * BK];
  __shared__ float rowm[256], rowinv[256];

  const int f = blockIdx.x;               // [0,256)
  const int z = f >> 6;                   // split slice
  const int q0 = f & 63;
  const int t = (q0 & 7) * 8 + (q0 >> 3); // XCD swizzle within slice
  const int m0 = (t >> 2) * 256, n0 = (t & 3) * 256;
  const int kt0 = z * (SEQ / 4);
  const int K = SEQ, N = DIM;
  ushort* C = Part + (size_t)z * SEQ * DIM;

  const int tid = threadIdx.x;
  const int wave = tid >> 6, lane = tid & 63;
  const int l31 = lane & 31, khalf = lane >> 5;
  const int wm = (wave & 1) * 128, wn = (wave >> 1) * 64;

  const int srow = tid >> 3;
  const int skey = ((srow & 7) ^ ((srow >> 3) & 3));
  const int sce = (((tid & 7) ^ skey) * 8);
  const int rk = (l31 & 7) ^ ((l31 >> 3) & 3);

  // finalize per-row softmax stats for this block's 256 rows (LSE merge of 16 blocks)
  if (tid < 256) {
    float mg = -3.4e38f;
#pragma unroll
    for (int cb = 0; cb < 16; cb++)
      mg = fmaxf(mg, Stats[(size_t)cb * SEQ + m0 + tid].x);
    float sg = 0.f;
#pragma unroll
    for (int cb = 0; cb < 16; cb++) {
      float2 st = Stats[(size_t)cb * SEQ + m0 + tid];
      sg += st.y * __expf(st.x - mg);
    }
    rowm[tid] = mg;
    rowinv[tid] = 1.0f / sg;
  }

  f32x16 acc[4][2];
#pragma unroll
  for (int i = 0; i < 4; i++)
#pragma unroll
    for (int j = 0; j < 2; j++)
#pragma unroll
      for (int r = 0; r < 16; r++) acc[i][j][r] = 0.f;

  const ushort* Abase = S + (size_t)(m0 + srow) * K + sce;
  const ushort* Bbase = Vt + (size_t)(n0 + srow) * K + sce;
  const int ldsbase = wave * 512;
  const int ntiles = (SEQ / 4) >> 6;  // 16

  // prologue: A tile0 -> regs, B tile0 -> LDS
  u16x8 areg[4];
#pragma unroll
  for (int q = 0; q < 4; q++)
    areg[q] = *reinterpret_cast<const u16x8*>(Abase + (size_t)q * 64 * K + kt0);
#pragma unroll
  for (int q = 0; q < 4; q++)
    __builtin_amdgcn_global_load_lds((const as1_void*)(Bbase + (size_t)q * 64 * K + kt0),
                                     (as3_void*)&Bs[0][ldsbase + q * 4096], 16, 0, 0);
  __syncthreads();  // rowm/rowinv visible; B tile0 landed

  float rm_[4], ri_[4];
#pragma unroll
  for (int q = 0; q < 4; q++) {
    rm_[q] = rowm[srow + q * 64];
    ri_[q] = rowinv[srow + q * 64];
  }
#pragma unroll
  for (int q = 0; q < 4; q++) {
    u16x8 o;
#pragma unroll
    for (int k2 = 0; k2 < 8; k2++)
      o[k2] = f2h(__expf(h2f(areg[q][k2]) - rm_[q]) * ri_[q]);
    *reinterpret_cast<u16x8*>(&As[0][ldsbase + q * 4096 + (lane & 63) * 8]) = o;
  }
  __syncthreads();  // As tile0 visible

  for (int tt = 0; tt < ntiles; ++tt) {
    const int cur = tt & 1, nb = cur ^ 1;
    const int nkt = kt0 + (tt + 1) * BK;
    const bool pf = (tt + 1 < ntiles);
    const ushort* As_c = As[cur];
    const ushort* Bs_c = Bs[cur];
#pragma unroll
    for (int ks = 0; ks < 4; ks++) {
      f16x8 af[4], bf2[2];
      const int co = (((ks * 2 + khalf)) ^ rk) * 8;
#pragma unroll
      for (int i = 0; i < 4; i++)
        af[i] = *reinterpret_cast<const f16x8*>(&As_c[(wm + i * 32 + l31) * BK + co]);
#pragma unroll
      for (int j = 0; j < 2; j++)
        bf2[j] = *reinterpret_cast<const f16x8*>(&Bs_c[(wn + j * 32 + l31) * BK + co]);
      if (pf && ks == 0) {
#pragma unroll
        for (int q = 0; q < 4; q++)
          areg[q] = *reinterpret_cast<const u16x8*>(Abase + (size_t)q * 64 * K + nkt);
      }
      if (pf && ks == 1) {
#pragma unroll
        for (int q = 0; q < 4; q++)
          __builtin_amdgcn_global_load_lds((const as1_void*)(Bbase + (size_t)q * 64 * K + nkt),
                                           (as3_void*)&Bs[nb][ldsbase + q * 4096], 16, 0, 0);
      }
      __builtin_amdgcn_s_barrier();
      __builtin_amdgcn_s_setprio(1);
#pragma unroll
      for (int i = 0; i < 4; i++)
#pragma unroll
        for (int j = 0; j < 2; j++)
          acc[i][j] = __builtin_amdgcn_mfma_f32_32x32x16_f16(af[i], bf2[j], acc[i][j], 0, 0, 0);
      __builtin_amdgcn_s_setprio(0);
      if (ks < 3) __builtin_amdgcn_s_barrier();
    }
    if (pf) {
      // transform + write next A tile into the buffer just vacated (disjoint from As_c)
#pragma unroll
      for (int q = 0; q < 4; q++) {
        u16x8 o;
#pragma unroll
        for (int k2 = 0; k2 < 8; k2++)
          o[k2] = f2h(__expf(h2f(areg[q][k2]) - rm_[q]) * ri_[q]);
        *reinterpret_cast<u16x8*>(&As[nb][ldsbase + q * 4096 + (lane & 63) * 8]) = o;
      }
    }
    __syncthreads();  // tile boundary: ds_writes + B loads complete
  }

#pragma unroll
  for (int i = 0; i < 4; i++)
#pragma unroll
    for (int j = 0; j < 2; j++)
#pragma unroll
      for (int r = 0; r < 16; r++) {
        int row = m0 + wm + i * 32 + (r & 3) + 8 * (r >> 2) + 4 * khalf;
        int col = n0 + wn + j * 32 + l31;
        C[(size_t)row * N + col] = f2h(acc[i][j][r]);
      }
}

__global__ void reduce4_kernel(const ushort* __restrict__ Part, float* __restrict__ out, int n8) {
  int i = blockIdx.x * blockDim.x + threadIdx.x;
  if (i >= n8) return;
  const f16x8* p0 = reinterpret_cast<const f16x8*>(Part);
  const f16x8* p1 = p0 + n8;
  const f16x8* p2 = p1 + n8;
  const f16x8* p3 = p2 + n8;
  f16x8 a = p0[i], b = p1[i], c = p2[i], d = p3[i];
  float4 lo, hi;
  lo.x = (float)a[0] + (float)b[0] + (float)c[0] + (float)d[0];
  lo.y = (float)a[1] + (float)b[1] + (float)c[1] + (float)d[1];
  lo.z = (float)a[2] + (float)b[2] + (float)c[2] + (float)d[2];
  lo.w = (float)a[3] + (float)b[3] + (float)c[3] + (float)d[3];
  hi.x = (float)a[4] + (float)b[4] + (float)c[4] + (float)d[4];
  hi.y = (float)a[5] + (float)b[5] + (float)c[5] + (float)d[5];
  hi.z = (float)a[6] + (float)b[6] + (float)c[6] + (float)d[6];
  hi.w = (float)a[7] + (float)b[7] + (float)c[7] + (float)d[7];
  reinterpret_cast<float4*>(out)[i * 2] = lo;
  reinterpret_cast<float4*>(out)[i * 2 + 1] = hi;
}

extern "C" void kernel_launch(void* const* d_in, const int* in_sizes, int n_in,
                              void* d_out, int out_size, void* d_ws, size_t ws_size,
                              hipStream_t stream) {
  const float* X = (const float*)d_in[0];
  const float* Wk = (const float*)d_in[1];
  const float* Wv = (const float*)d_in[2];
  const float* Wq = (const float*)d_in[3];

  char* ws = (char*)d_ws;
  size_t off = 0;
  ushort* Xh = (ushort*)(ws + off); off += (size_t)SEQ * DIM * 2;      // 8 MB
  ushort* Wt = (ushort*)(ws + off); off += (size_t)3 * DIM * DIM * 2;  // 6 MB
  ushort* Kh = (ushort*)(ws + off); off += (size_t)SEQ * DIM * 2;      // 8 MB
  ushort* Qh = (ushort*)(ws + off); off += (size_t)SEQ * DIM * 2;      // 8 MB
  ushort* Vt = (ushort*)(ws + off); off += (size_t)SEQ * DIM * 2;      // 8 MB
  ushort* S = (ushort*)(ws + off);  off += (size_t)SEQ * SEQ * 2;      // 32 MB (stays live for out!)
  ushort* P = (ushort*)(ws + off);  off += (size_t)SEQ * SEQ * 2;      // 32 MB (now holds Part)

  // Stats[16][SEQ] float2 = 512 KB, aliased into Xh (dead after proj; rewritten
  // by convert each iteration before proj reads it — stream-serial, safe).
  float2* Stats = (float2*)Xh;
  ushort* Part = P;  // S must NOT be aliased anymore — out reads S while writing Part

  convert_all_kernel<<<dim3(32, 32, 4), dim3(32, 8), 0, stream>>>(X, Wk, Wv, Wq, Xh, Wt);
  proj256_kernel<<<256, 512, 0, stream>>>(Xh, Wt, Kh, Qh, Vt);
  score256_kernel<<<256, 512, 0, stream>>>(Kh, Qh, S, Stats);
  out_sm256_kernel<<<256, 512, 0, stream>>>(S, Vt, Stats, Part);
  reduce4_kernel<<<SEQ * DIM / 8 / 256, 256, 0, stream>>>(Part, (float*)d_out, SEQ * DIM / 8);
}

// Round 5
// 221.084 us; speedup vs baseline: 1.0901x; 1.0901x over previous
//
#include <hip/hip_runtime.h>
#include <hip/hip_fp16.h>
#include <cstdint>

#define SEQ 4096
#define DIM 1024

typedef _Float16 f16x8 __attribute__((ext_vector_type(8)));
typedef float f32x16 __attribute__((ext_vector_type(16)));
typedef __attribute__((address_space(1))) void as1_void;
typedef __attribute__((address_space(3))) void as3_void;

__device__ __forceinline__ ushort f2h(float f) {
  _Float16 h = (_Float16)f;
  return __builtin_bit_cast(ushort, h);
}

// ---------------- fused conversions: z<3 -> W transpose+cvt, z==3 -> X cvt ----------------
__global__ void convert_all_kernel(const float* __restrict__ X, const float* __restrict__ Wk,
                                   const float* __restrict__ Wv, const float* __restrict__ Wq,
                                   ushort* __restrict__ Xh, ushort* __restrict__ Wt) {
  const int z = blockIdx.z;
  const int tx = threadIdx.x, ty = threadIdx.y;  // (32,8)
  if (z == 3) {
    const int bid = blockIdx.y * 32 + blockIdx.x;
    const int t = ty * 32 + tx;
#pragma unroll
    for (int k = 0; k < 4; k++) {
      int i = bid * 1024 + k * 256 + t;
      float4 v = reinterpret_cast<const float4*>(X)[i];
      ushort4 o = { f2h(v.x), f2h(v.y), f2h(v.z), f2h(v.w) };
      reinterpret_cast<ushort4*>(Xh)[i] = o;
    }
    return;
  }
  __shared__ float tile[32][33];
  const float* W = (z == 0) ? Wk : (z == 1) ? Wv : Wq;
  int n0 = blockIdx.x * 32, k0 = blockIdx.y * 32;
#pragma unroll
  for (int r = 0; r < 4; r++) {
    int k = ty + r * 8;
    tile[k][tx] = W[(size_t)(k0 + k) * DIM + n0 + tx];
  }
  __syncthreads();
  ushort* out = Wt + (size_t)z * DIM * DIM;
#pragma unroll
  for (int r = 0; r < 4; r++) {
    int n = ty + r * 8;
    out[(size_t)(n0 + n) * DIM + k0 + tx] = f2h(tile[tx][n]);
  }
}

// ---------------- core GEMM tile A: 128x128 block, 4 waves, 64x64/wave ----------------
// Single-buffered, 2-barrier per K-tile (m97-class structure; best plain-HIP operating
// point for 128^2 per measured ladder). XOR chunk swizzle key(r)=(r&7)^((r>>3)&3):
// verified 0 bank conflicts. F16_OUT=false writes f32 directly (used by out128).
template <bool F16_OUT>
__device__ __forceinline__ void gemm_tile(const ushort* __restrict__ A,
                                          const ushort* __restrict__ B,
                                          void* __restrict__ C,
                                          int N, int K, int m0, int n0,
                                          int kt0, int ktend) {
  constexpr int BK = 64;
  __shared__ __align__(16) ushort As[128 * BK];
  __shared__ __align__(16) ushort Bs[128 * BK];
  const int tid = threadIdx.x;
  const int wave = tid >> 6, lane = tid & 63;
  const int l31 = lane & 31, khalf = lane >> 5;
  const int wm = (wave & 1) * 64, wn = (wave >> 1) * 64;

  const int srow = tid >> 3;
  const int skey = ((srow & 7) ^ ((srow >> 3) & 3));
  const int sce = (((tid & 7) ^ skey) * 8);
  const int rk = (l31 & 7) ^ ((l31 >> 3) & 3);

  f32x16 acc[2][2];
#pragma unroll
  for (int i = 0; i < 2; i++)
#pragma unroll
    for (int j = 0; j < 2; j++)
#pragma unroll
      for (int r = 0; r < 16; r++) acc[i][j][r] = 0.f;

  for (int kt = kt0; kt < ktend; kt += BK) {
    __syncthreads();
#pragma unroll
    for (int q = 0; q < 4; q++) {
      const ushort* ga = A + (size_t)(m0 + srow + q * 32) * K + kt + sce;
      __builtin_amdgcn_global_load_lds((const as1_void*)ga,
                                       (as3_void*)&As[wave * 512 + q * 2048], 16, 0, 0);
    }
#pragma unroll
    for (int q = 0; q < 4; q++) {
      const ushort* gb = B + (size_t)(n0 + srow + q * 32) * K + kt + sce;
      __builtin_amdgcn_global_load_lds((const as1_void*)gb,
                                       (as3_void*)&Bs[wave * 512 + q * 2048], 16, 0, 0);
    }
    __syncthreads();
#pragma unroll
    for (int ks = 0; ks < 4; ks++) {
      f16x8 af[2], bfr[2];
      const int ck = (ks * 2 + khalf);
#pragma unroll
      for (int i = 0; i < 2; i++)
        af[i] = *reinterpret_cast<const f16x8*>(
            &As[(wm + i * 32 + l31) * BK + ((ck ^ rk) * 8)]);
#pragma unroll
      for (int j = 0; j < 2; j++)
        bfr[j] = *reinterpret_cast<const f16x8*>(
            &Bs[(wn + j * 32 + l31) * BK + ((ck ^ rk) * 8)]);
#pragma unroll
      for (int i = 0; i < 2; i++)
#pragma unroll
        for (int j = 0; j < 2; j++)
          acc[i][j] = __builtin_amdgcn_mfma_f32_32x32x16_f16(af[i], bfr[j], acc[i][j], 0, 0, 0);
    }
  }

  // epilogue: 32x32 C/D layout col=lane&31, row=(reg&3)+8*(reg>>2)+4*(lane>>5)  [m74/m101]
#pragma unroll
  for (int i = 0; i < 2; i++)
#pragma unroll
    for (int j = 0; j < 2; j++)
#pragma unroll
      for (int r = 0; r < 16; r++) {
        int row = m0 + wm + i * 32 + (r & 3) + 8 * (r >> 2) + 4 * khalf;
        int col = n0 + wn + j * 32 + l31;
        if (F16_OUT)
          reinterpret_cast<ushort*>(C)[(size_t)row * N + col] = f2h(acc[i][j][r]);
        else
          reinterpret_cast<float*>(C)[(size_t)row * N + col] = acc[i][j][r];
      }
}

// ---------------- 256x256 GEMM (R1 measured-best schedule): 8 waves, 128x64/wave ----------
// 4 k-slice phases per K-tile; prefetch of tile t+1 at ks0 (A) / ks1 (B) into the other
// buffer; setprio(1) around each 8-MFMA cluster; boundary __syncthreads drains staging.
// XOR chunk swizzle key(r)=(r&7)^((r>>3)&3); 0 bank conflicts (verified R1 rocprof).
__device__ __forceinline__ void gemm_tile256(const ushort* __restrict__ A,
                                             const ushort* __restrict__ B,
                                             ushort* __restrict__ C,
                                             int N, int K, int m0, int n0,
                                             int kt0, int ktend) {
  constexpr int BK = 64;
  __shared__ __align__(16) ushort As[2][256 * BK];  // 2 x 32 KB
  __shared__ __align__(16) ushort Bs[2][256 * BK];  // 2 x 32 KB
  const int tid = threadIdx.x;                       // [0,512)
  const int wave = tid >> 6, lane = tid & 63;
  const int l31 = lane & 31, khalf = lane >> 5;
  const int wm = (wave & 1) * 128, wn = (wave >> 1) * 64;

  const int srow = tid >> 3;                         // [0,64)
  const int skey = ((srow & 7) ^ ((srow >> 3) & 3));
  const int sce = (((tid & 7) ^ skey) * 8);
  const int rk = (l31 & 7) ^ ((l31 >> 3) & 3);

  f32x16 acc[4][2];
#pragma unroll
  for (int i = 0; i < 4; i++)
#pragma unroll
    for (int j = 0; j < 2; j++)
#pragma unroll
      for (int r = 0; r < 16; r++) acc[i][j][r] = 0.f;

  const ushort* Abase = A + (size_t)(m0 + srow) * K + sce;
  const ushort* Bbase = B + (size_t)(n0 + srow) * K + sce;
  const int ldsbase = wave * 512;

  const int ntiles = (ktend - kt0) >> 6;

  // prologue: stage tile 0 fully into buf 0
#pragma unroll
  for (int q = 0; q < 4; q++)
    __builtin_amdgcn_global_load_lds((const as1_void*)(Abase + (size_t)q * 64 * K + kt0),
                                     (as3_void*)&As[0][ldsbase + q * 4096], 16, 0, 0);
#pragma unroll
  for (int q = 0; q < 4; q++)
    __builtin_amdgcn_global_load_lds((const as1_void*)(Bbase + (size_t)q * 64 * K + kt0),
                                     (as3_void*)&Bs[0][ldsbase + q * 4096], 16, 0, 0);
  __syncthreads();

  for (int tt = 0; tt < ntiles; ++tt) {
    const int cur = tt & 1, nb = cur ^ 1;
    const int nkt = kt0 + (tt + 1) * BK;
    const bool pf = (tt + 1 < ntiles);
    const ushort* As_c = As[cur];
    const ushort* Bs_c = Bs[cur];
#pragma unroll
    for (int ks = 0; ks < 4; ks++) {
      f16x8 af[4], bf2[2];
      const int co = (((ks * 2 + khalf)) ^ rk) * 8;
#pragma unroll
      for (int i = 0; i < 4; i++)
        af[i] = *reinterpret_cast<const f16x8*>(&As_c[(wm + i * 32 + l31) * BK + co]);
#pragma unroll
      for (int j = 0; j < 2; j++)
        bf2[j] = *reinterpret_cast<const f16x8*>(&Bs_c[(wn + j * 32 + l31) * BK + co]);
      if (pf && ks == 0) {
#pragma unroll
        for (int q = 0; q < 4; q++)
          __builtin_amdgcn_global_load_lds((const as1_void*)(Abase + (size_t)q * 64 * K + nkt),
                                           (as3_void*)&As[nb][ldsbase + q * 4096], 16, 0, 0);
      }
      if (pf && ks == 1) {
#pragma unroll
        for (int q = 0; q < 4; q++)
          __builtin_amdgcn_global_load_lds((const as1_void*)(Bbase + (size_t)q * 64 * K + nkt),
                                           (as3_void*)&Bs[nb][ldsbase + q * 4096], 16, 0, 0);
      }
      __builtin_amdgcn_s_barrier();
      __builtin_amdgcn_s_setprio(1);
#pragma unroll
      for (int i = 0; i < 4; i++)
#pragma unroll
        for (int j = 0; j < 2; j++)
          acc[i][j] = __builtin_amdgcn_mfma_f32_32x32x16_f16(af[i], bf2[j], acc[i][j], 0, 0, 0);
      __builtin_amdgcn_s_setprio(0);
      if (ks < 3) __builtin_amdgcn_s_barrier();
    }
    __syncthreads();  // tile boundary
  }

#pragma unroll
  for (int i = 0; i < 4; i++)
#pragma unroll
    for (int j = 0; j < 2; j++)
#pragma unroll
      for (int r = 0; r < 16; r++) {
        int row = m0 + wm + i * 32 + (r & 3) + 8 * (r >> 2) + 4 * khalf;
        int col = n0 + wn + j * 32 + l31;
        C[(size_t)row * N + col] = f2h(acc[i][j][r]);
      }
}

// ---------------- fused K/Q/V^T projections (768 blocks, 128^2 tiles, 3+/CU) ----------------
__global__ __launch_bounds__(256) void proj_kernel(const ushort* __restrict__ Xh,
                                                   const ushort* __restrict__ Wt,
                                                   ushort* __restrict__ Kh,
                                                   ushort* __restrict__ Qh,
                                                   ushort* __restrict__ Vt) {
  const int z = blockIdx.z;
  const ushort* A;
  const ushort* B;
  ushort* C;
  int N, m0, n0;
  if (z < 2) {
    A = Xh;
    B = Wt + (size_t)(z == 0 ? 0 : 2) * DIM * DIM;
    C = (z == 0) ? Kh : Qh;
    N = DIM;
    m0 = (blockIdx.x >> 3) * 128;   // 32 m-tiles
    n0 = (blockIdx.x & 7) * 128;    // 8 n-tiles
  } else {
    A = Wt + (size_t)DIM * DIM;     // V^T = Wv^T(K-contig) x Xh: M=1024, N=4096
    B = Xh;
    C = Vt;
    N = SEQ;
    m0 = (blockIdx.x >> 5) * 128;   // 8 m-tiles (M=1024)
    n0 = (blockIdx.x & 31) * 128;   // 32 n-tiles
  }
  gemm_tile<true>(A, B, C, N, DIM, m0, n0, 0, DIM);
}

// ---------------- S = K @ Q^T (fp16), 256x256 tiles, XCD-swizzled ----------------
__global__ __launch_bounds__(512, 2) void score256_kernel(const ushort* __restrict__ Kh,
                                                          const ushort* __restrict__ Qh,
                                                          ushort* __restrict__ S) {
  const int f = blockIdx.x;               // [0,256)
  const int t = (f & 7) * 32 + (f >> 3);  // XCD-contiguous (256 % 8 == 0, bijective)
  gemm_tile256(Kh, Qh, S, SEQ, DIM, (t >> 4) * 256, (t & 15) * 256, 0, DIM);
}

// ---------------- row softmax: one wave per row ----------------
__global__ __launch_bounds__(256) void softmax_kernel(const ushort* __restrict__ S,
                                                      ushort* __restrict__ P) {
  const int wave = threadIdx.x >> 6, lane = threadIdx.x & 63;
  const int row = blockIdx.x * 4 + wave;
  const ushort* s = S + (size_t)row * SEQ;
  float v[64];
#pragma unroll
  for (int i = 0; i < 8; i++) {
    f16x8 h = reinterpret_cast<const f16x8*>(s)[i * 64 + lane];
#pragma unroll
    for (int j = 0; j < 8; j++) v[i * 8 + j] = (float)h[j];
  }
  float m = v[0];
#pragma unroll
  for (int j = 1; j < 64; j++) m = fmaxf(m, v[j]);
#pragma unroll
  for (int o = 32; o > 0; o >>= 1) m = fmaxf(m, __shfl_xor(m, o, 64));
  float sum = 0.f;
#pragma unroll
  for (int j = 0; j < 64; j++) {
    v[j] = __expf(v[j] - m);
    sum += v[j];
  }
#pragma unroll
  for (int o = 32; o > 0; o >>= 1) sum += __shfl_xor(sum, o, 64);
  float inv = 1.0f / sum;
  ushort* p = P + (size_t)row * SEQ;
#pragma unroll
  for (int i = 0; i < 8; i++) {
    f16x8 h;
#pragma unroll
    for (int j = 0; j < 8; j++) h[j] = (_Float16)(v[i * 8 + j] * inv);
    reinterpret_cast<f16x8*>(p)[i * 64 + lane] = h;
  }
}

// ---------------- O = P @ V: 256 blocks of 128^2 tiles, full K, f32 direct out ----------
// M/128 x N/128 = 32 x 8 = 256 blocks: perfect occupancy with NO split-K, no partials,
// no reduce kernel. XCD swizzle groups m-tiles per XCD (P-panel L2 locality).
__global__ __launch_bounds__(256, 2) void out128_kernel(const ushort* __restrict__ P,
                                                        const ushort* __restrict__ Vt,
                                                        float* __restrict__ O) {
  const int f = blockIdx.x;               // [0,256)
  const int t = (f & 7) * 32 + (f >> 3);  // XCD-contiguous (bijective)
  const int mt = t >> 3, nt = t & 7;      // 32 x 8 tiles
  gemm_tile<false>(P, Vt, O, DIM, SEQ, mt * 128, nt * 128, 0, SEQ);
}

extern "C" void kernel_launch(void* const* d_in, const int* in_sizes, int n_in,
                              void* d_out, int out_size, void* d_ws, size_t ws_size,
                              hipStream_t stream) {
  const float* X = (const float*)d_in[0];
  const float* Wk = (const float*)d_in[1];
  const float* Wv = (const float*)d_in[2];
  const float* Wq = (const float*)d_in[3];

  char* ws = (char*)d_ws;
  size_t off = 0;
  ushort* Xh = (ushort*)(ws + off); off += (size_t)SEQ * DIM * 2;      // 8 MB
  ushort* Wt = (ushort*)(ws + off); off += (size_t)3 * DIM * DIM * 2;  // 6 MB
  ushort* Kh = (ushort*)(ws + off); off += (size_t)SEQ * DIM * 2;      // 8 MB
  ushort* Qh = (ushort*)(ws + off); off += (size_t)SEQ * DIM * 2;      // 8 MB
  ushort* Vt = (ushort*)(ws + off); off += (size_t)SEQ * DIM * 2;      // 8 MB
  ushort* S = (ushort*)(ws + off);  off += (size_t)SEQ * SEQ * 2;      // 32 MB
  ushort* P = (ushort*)(ws + off);  off += (size_t)SEQ * SEQ * 2;      // 32 MB

  convert_all_kernel<<<dim3(32, 32, 4), dim3(32, 8), 0, stream>>>(X, Wk, Wv, Wq, Xh, Wt);
  proj_kernel<<<dim3(256, 1, 3), 256, 0, stream>>>(Xh, Wt, Kh, Qh, Vt);
  score256_kernel<<<256, 512, 0, stream>>>(Kh, Qh, S);
  softmax_kernel<<<1024, 256, 0, stream>>>(S, P);
  out128_kernel<<<256, 256, 0, stream>>>(P, Vt, (float*)d_out);
}